// Round 3
// baseline (4821.383 us; speedup 1.0000x reference)
//
#include <hip/hip_runtime.h>
#include <hip/hip_bf16.h>
#include <stdint.h>
#include <stddef.h>

#define NPTS 8192
#define KNN  12
#define CH   128
#define FFD  512
#define MEDGE (NPTS * KNN)   // 98304 edges

typedef __attribute__((ext_vector_type(8))) _Float16 half8;
typedef __attribute__((ext_vector_type(4))) float f32x4;

__device__ __forceinline__ float wave_sum(float v) {
#pragma unroll
  for (int off = 32; off > 0; off >>= 1) v += __shfl_xor(v, off, 64);
  return v;
}
__device__ __forceinline__ float sigm_(float x) { return 1.0f / (1.0f + expf(-x)); }
__device__ __forceinline__ float gelu_(float x) { return 0.5f * x * (1.0f + erff(x * 0.7071067811865475f)); }

// ---------------------------------------------------------------------------
// KNN (stable top-12 by (dist, idx)) + RBF embed  -> nbr [N,K], v0 [N,K,C] f32
// merge phase: wave shuffle-min + 4-entry LDS combine (2 barriers/round)
// ---------------------------------------------------------------------------
__global__ __launch_bounds__(256)
void knn_embed(const float* __restrict__ coords, int* __restrict__ nbr, float* __restrict__ v0)
{
#pragma clang fp contract(off)
  __shared__ unsigned long long wmin[4];
  __shared__ unsigned long long sel[KNN];
  const int i = blockIdx.x;
  const int tid = threadIdx.x;
  const int lane = tid & 63;
  const int wv = tid >> 6;
  const float cx = coords[3 * i + 0];
  const float cy = coords[3 * i + 1];
  const float cz = coords[3 * i + 2];
  unsigned long long best[KNN];
#pragma unroll
  for (int q = 0; q < KNN; ++q) best[q] = ~0ULL;
  for (int j = tid; j < NPTS; j += 256) {
    float dx = cx - coords[3 * j + 0];
    float dy = cy - coords[3 * j + 1];
    float dz = cz - coords[3 * j + 2];
    float d2 = dx * dx + dy * dy + dz * dz;   // contract off: matches numpy order
    float d = sqrtf(d2);
    unsigned long long key = (((unsigned long long)__float_as_uint(d)) << 32) | (unsigned int)j;
    if (key < best[KNN - 1]) {
      best[KNN - 1] = key;
#pragma unroll
      for (int q = KNN - 2; q >= 0; --q) {
        if (best[q + 1] < best[q]) { unsigned long long t = best[q]; best[q] = best[q + 1]; best[q + 1] = t; }
      }
    }
  }
  int p = 0;
  for (int r = 0; r < KNN; ++r) {
    unsigned long long c = ~0ULL;
#pragma unroll
    for (int q = 0; q < KNN; ++q) if (q == p) c = best[q];
    unsigned long long m = c;
#pragma unroll
    for (int off = 32; off > 0; off >>= 1) {
      unsigned long long o = __shfl_xor(m, off, 64);
      if (o < m) m = o;
    }
    if (lane == 0) wmin[wv] = m;
    __syncthreads();
    unsigned long long g = wmin[0];
    if (wmin[1] < g) g = wmin[1];
    if (wmin[2] < g) g = wmin[2];
    if (wmin[3] < g) g = wmin[3];
    if (c == g) ++p;              // keys unique -> exactly one popper
    if (tid == 0) sel[r] = g;
    __syncthreads();
  }
  if (tid < KNN) nbr[i * KNN + tid] = (int)(unsigned int)(sel[tid] & 0xFFFFFFFFULL);
  for (int idx = tid; idx < KNN * CH; idx += 256) {
    int k = idx >> 7, ch = idx & 127;
    float d = __uint_as_float((unsigned int)(sel[k] >> 32));
    float sig = (float)(1.0 + 4.0 * (double)ch / 127.0);     // linspace(1,5,128)
    float g = expf((-(d * d)) / (2.0f * (sig * sig)));
    v0[(size_t)(i * KNN + k) * CH + ch] = (g > 0.1f) ? g : 0.0f;
  }
}

// ---------------------------------------------------------------------------
// transpose index: tidx[i*K+k] = j*K+pos where nbr[j,pos]==i, else -1
// ---------------------------------------------------------------------------
__global__ __launch_bounds__(256)
void build_tidx(const int* __restrict__ nbr, int* __restrict__ tidx)
{
  int e = blockIdx.x * 256 + threadIdx.x;
  if (e >= MEDGE) return;
  int i = e / KNN;
  int j = nbr[e];
  int res = -1;
#pragma unroll
  for (int t = 0; t < KNN; ++t) {
    if (nbr[j * KNN + t] == i) { res = j * KNN + t; break; }
  }
  tidx[e] = res;
}

// ---------------------------------------------------------------------------
// one-launch weight prep: 8 transpose+cast jobs  dst[b][c][r] = f16(src[b][r][c])
// ---------------------------------------------------------------------------
struct PrepArgs {
  const float* src[8];
  _Float16* dst[8];
  int R[8];
  int C[8];
  int total[8];
};

__global__ __launch_bounds__(256)
void prep_weights(PrepArgs pa)
{
  int g = blockIdx.y;
  int idx = blockIdx.x * 256 + threadIdx.x;
  if (idx >= pa.total[g]) return;
  int R = pa.R[g], C2 = pa.C[g];
  int rc = R * C2;
  int b = idx / rc;
  int rem = idx - b * rc;
  int c = rem / R;
  int r = rem - c * R;
  pa.dst[g][idx] = (_Float16)(pa.src[g][((size_t)b * R + r) * C2 + c]);
}

// ---------------------------------------------------------------------------
// shared helpers for MFMA tiles
// ---------------------------------------------------------------------------
__device__ __forceinline__ void stage_w(const _Float16* __restrict__ src, int srcStride,
                                        _Float16 (*dst)[136], int tid)
{
#pragma unroll
  for (int it = 0; it < 8; ++it) {
    int chunk = tid + it * 256;          // 2048 chunks of 8 f16 = 128 rows x 16
    int row = chunk >> 4;
    int ko = (chunk & 15) * 8;
    *(half8*)&dst[row][ko] = *(const half8*)(src + (size_t)row * srcStride + ko);
  }
}

// 2 row-tiles x 8 col-tiles per wave (128-row block)
__device__ __forceinline__ void mm2x8(const half8 xf[2][4], const _Float16 (*ws_)[136],
                                      int l16, int quad, f32x4 acc[2][8])
{
#pragma unroll
  for (int nt = 0; nt < 8; ++nt) {
    half8 wf[4];
#pragma unroll
    for (int kt = 0; kt < 4; ++kt)
      wf[kt] = *(const half8*)&ws_[nt * 16 + l16][kt * 32 + quad * 8];
#pragma unroll
    for (int rt = 0; rt < 2; ++rt) {
      f32x4 a = {0.0f, 0.0f, 0.0f, 0.0f};
#pragma unroll
      for (int kt = 0; kt < 4; ++kt)
        a = __builtin_amdgcn_mfma_f32_16x16x32_f16(xf[rt][kt], wf[kt], a, 0, 0, 0);
      acc[rt][nt] = a;
    }
  }
}

// LN of one 128-wide row -> fp16 LDS row (wave-cooperative)
__device__ __forceinline__ void ln_row(const float* __restrict__ vp, float g1, float g2,
                                       float b1, float b2, _Float16* dst, int lane)
{
  float x1 = vp[lane], x2 = vp[lane + 64];
  float m = wave_sum(x1 + x2) * (1.0f / 128.0f);
  float d1 = x1 - m, d2 = x2 - m;
  float var = wave_sum(d1 * d1 + d2 * d2) * (1.0f / 128.0f);
  float rs = 1.0f / sqrtf(var + 1e-5f);
  dst[lane]      = (_Float16)(d1 * rs * g1 + b1);
  dst[lane + 64] = (_Float16)(d2 * rs * g2 + b2);
}

// ---------------------------------------------------------------------------
// LN(v) -> a = sig(x@Wga+bga)*(x@Wa+ba), b = ..., go = sig(x@Wgo+bgo)  (f16)
// 128-row M-tile per block
// ---------------------------------------------------------------------------
__global__ __launch_bounds__(256)
void ln_gemm5(const float* __restrict__ vin,
              const float* __restrict__ ln_g, const float* __restrict__ ln_b,
              const _Float16* __restrict__ wtA,  const float* __restrict__ bA,
              const _Float16* __restrict__ wtGA, const float* __restrict__ bGA,
              const _Float16* __restrict__ wtB,  const float* __restrict__ bB,
              const _Float16* __restrict__ wtGB, const float* __restrict__ bGB,
              const _Float16* __restrict__ wtGO, const float* __restrict__ bGO,
              _Float16* __restrict__ aout, _Float16* __restrict__ bout,
              _Float16* __restrict__ goout)
{
  __shared__ alignas(16) _Float16 xs[128][136];
  __shared__ alignas(16) _Float16 ws_[128][136];
  const int tid = threadIdx.x;
  const int lane = tid & 63;
  const int w = tid >> 6;
  const int quad = lane >> 4;
  const int l16 = lane & 15;
  const int rowBase = blockIdx.x * 128;

  float gg1 = ln_g[lane], gg2 = ln_g[lane + 64];
  float gb1 = ln_b[lane], gb2 = ln_b[lane + 64];
  for (int r = 0; r < 32; ++r) {
    int row = w * 32 + r;
    ln_row(vin + (size_t)(rowBase + row) * CH, gg1, gg2, gb1, gb2, &xs[row][0], lane);
  }
  __syncthreads();
  stage_w(wtA, CH, ws_, tid);
  __syncthreads();

  half8 xf[2][4];
#pragma unroll
  for (int rt = 0; rt < 2; ++rt)
#pragma unroll
    for (int kt = 0; kt < 4; ++kt)
      xf[rt][kt] = *(const half8*)&xs[w * 32 + rt * 16 + l16][kt * 32 + quad * 8];

  f32x4 accP[2][8], accQ[2][8];

  // ---- a ----
  mm2x8(xf, ws_, l16, quad, accP);
  __syncthreads();
  stage_w(wtGA, CH, ws_, tid);
  __syncthreads();
  mm2x8(xf, ws_, l16, quad, accQ);
#pragma unroll
  for (int nt = 0; nt < 8; ++nt) {
    int col = nt * 16 + l16;
    float bv = bA[col], bgv = bGA[col];
#pragma unroll
    for (int rt = 0; rt < 2; ++rt)
#pragma unroll
      for (int r = 0; r < 4; ++r) {
        int row = rowBase + w * 32 + rt * 16 + quad * 4 + r;
        aout[(size_t)row * CH + col] = (_Float16)(sigm_(accQ[rt][nt][r] + bgv) * (accP[rt][nt][r] + bv));
      }
  }
  // ---- b ----
  __syncthreads();
  stage_w(wtB, CH, ws_, tid);
  __syncthreads();
  mm2x8(xf, ws_, l16, quad, accP);
  __syncthreads();
  stage_w(wtGB, CH, ws_, tid);
  __syncthreads();
  mm2x8(xf, ws_, l16, quad, accQ);
#pragma unroll
  for (int nt = 0; nt < 8; ++nt) {
    int col = nt * 16 + l16;
    float bv = bB[col], bgv = bGB[col];
#pragma unroll
    for (int rt = 0; rt < 2; ++rt)
#pragma unroll
      for (int r = 0; r < 4; ++r) {
        int row = rowBase + w * 32 + rt * 16 + quad * 4 + r;
        bout[(size_t)row * CH + col] = (_Float16)(sigm_(accQ[rt][nt][r] + bgv) * (accP[rt][nt][r] + bv));
      }
  }
  // ---- go ----
  __syncthreads();
  stage_w(wtGO, CH, ws_, tid);
  __syncthreads();
  mm2x8(xf, ws_, l16, quad, accP);
#pragma unroll
  for (int nt = 0; nt < 8; ++nt) {
    int col = nt * 16 + l16;
    float bgv = bGO[col];
#pragma unroll
    for (int rt = 0; rt < 2; ++rt)
#pragma unroll
      for (int r = 0; r < 4; ++r) {
        int row = rowBase + w * 32 + rt * 16 + quad * 4 + r;
        goout[(size_t)row * CH + col] = (_Float16)(sigm_(accP[rt][nt][r] + bgv));
      }
  }
}

// ---------------------------------------------------------------------------
// sparse triangle einsum + fused LN:  k[n,m,:] = LN_row(sum_t A(n,t,:)*B(nbr,t,:))
// output fp16 (gamma/beta applied). incoming=1 -> transpose-indexed A/B.
// ---------------------------------------------------------------------------
__global__ __launch_bounds__(256)
void tri_einsum_ln(const _Float16* __restrict__ a, const _Float16* __restrict__ b,
                   const int* __restrict__ nbr, const int* __restrict__ tidx,
                   const float* __restrict__ lng, const float* __restrict__ lnb,
                   _Float16* __restrict__ kout, int incoming)
{
  __shared__ float As[KNN][CH];
  __shared__ int bidx[KNN][KNN];
  __shared__ int nbr_s[KNN];
  __shared__ float part[6][4][2];
  const int n = blockIdx.x;
  const int tid = threadIdx.x;
  const int wv = tid >> 6;
  if (tid < KNN) nbr_s[tid] = nbr[n * KNN + tid];
  __syncthreads();
  if (tid < KNN * KNN) {
    int m = tid / KNN, t = tid - m * KNN;
    int j = nbr_s[m];
    bidx[m][t] = incoming ? tidx[j * KNN + t] : (j * KNN + t);
  }
  for (int idx = tid; idx < KNN * CH; idx += 256) {
    int t = idx >> 7, c = idx & 127;
    float av;
    if (incoming) {
      int ti = tidx[n * KNN + t];
      av = (ti >= 0) ? (float)(a[(size_t)ti * CH + c]) : 0.0f;
    } else {
      av = (float)(a[(size_t)(n * KNN + t) * CH + c]);
    }
    As[t][c] = av;
  }
  __syncthreads();
  const int c = tid & 127;
  const int mh = tid >> 7;
  const float gc = lng[c], bc = lnb[c];
  for (int mm = 0; mm < 6; ++mm) {
    int m = mm * 2 + mh;
    float acc = 0.0f;
#pragma unroll
    for (int t = 0; t < KNN; ++t) {
      int bi = bidx[m][t];
      float bv = (bi >= 0) ? (float)(b[(size_t)bi * CH + c]) : 0.0f;
      acc += As[t][c] * bv;
    }
    float s1 = wave_sum(acc);
    float s2 = wave_sum(acc * acc);
    if ((tid & 63) == 0) { part[mm][wv][0] = s1; part[mm][wv][1] = s2; }
    __syncthreads();
    int pb = mh * 2;
    float sum = part[mm][pb][0] + part[mm][pb + 1][0];
    float sq  = part[mm][pb][1] + part[mm][pb + 1][1];
    float mean = sum * (1.0f / 128.0f);
    float var = sq * (1.0f / 128.0f) - mean * mean;
    if (var < 0.0f) var = 0.0f;
    float rs = 1.0f / sqrtf(var + 1e-5f);
    kout[(size_t)(n * KNN + m) * CH + c] = (_Float16)((acc - mean) * rs * gc + bc);
  }
}

// ---------------------------------------------------------------------------
// v += go * (kln @ Wo + bo)   (kln already LN'ed fp16; 128-row tile)
// ---------------------------------------------------------------------------
__global__ __launch_bounds__(256)
void out_gemm(const _Float16* __restrict__ kln,
              const _Float16* __restrict__ wtO, const float* __restrict__ bO,
              const _Float16* __restrict__ goin, float* __restrict__ vio)
{
  __shared__ alignas(16) _Float16 ws_[128][136];
  const int tid = threadIdx.x;
  const int lane = tid & 63;
  const int w = tid >> 6;
  const int quad = lane >> 4;
  const int l16 = lane & 15;
  const int rowBase = blockIdx.x * 128;

  stage_w(wtO, CH, ws_, tid);
  half8 xf[2][4];
#pragma unroll
  for (int rt = 0; rt < 2; ++rt)
#pragma unroll
    for (int kt = 0; kt < 4; ++kt)
      xf[rt][kt] = *(const half8*)(kln + (size_t)(rowBase + w * 32 + rt * 16 + l16) * CH + kt * 32 + quad * 8);
  __syncthreads();

  f32x4 acc[2][8];
  mm2x8(xf, ws_, l16, quad, acc);
#pragma unroll
  for (int nt = 0; nt < 8; ++nt) {
    int col = nt * 16 + l16;
    float bv = bO[col];
#pragma unroll
    for (int rt = 0; rt < 2; ++rt)
#pragma unroll
      for (int r = 0; r < 4; ++r) {
        size_t off = (size_t)(rowBase + w * 32 + rt * 16 + quad * 4 + r) * CH + col;
        vio[off] += (float)(goin[off]) * (acc[rt][nt][r] + bv);
      }
  }
}

// ---------------------------------------------------------------------------
// FFN part 1: h = gelu(LN(v) @ W1 + b1)   (f16 out, [M,512]; 128-row tile)
// ---------------------------------------------------------------------------
__global__ __launch_bounds__(256)
void ffn1(const float* __restrict__ vin,
          const float* __restrict__ ln_g, const float* __restrict__ ln_b,
          const _Float16* __restrict__ wt1, const float* __restrict__ b1,
          _Float16* __restrict__ hout)
{
  __shared__ alignas(16) _Float16 xs[128][136];
  __shared__ alignas(16) _Float16 ws_[128][136];
  const int tid = threadIdx.x;
  const int lane = tid & 63;
  const int w = tid >> 6;
  const int quad = lane >> 4;
  const int l16 = lane & 15;
  const int rowBase = blockIdx.x * 128;

  float gg1 = ln_g[lane], gg2 = ln_g[lane + 64];
  float gb1 = ln_b[lane], gb2 = ln_b[lane + 64];
  for (int r = 0; r < 32; ++r) {
    int row = w * 32 + r;
    ln_row(vin + (size_t)(rowBase + row) * CH, gg1, gg2, gb1, gb2, &xs[row][0], lane);
  }

  half8 xf[2][4];
  f32x4 acc[2][8];
  bool xfLoaded = false;
  for (int cc = 0; cc < 4; ++cc) {
    __syncthreads();
    stage_w(wt1 + (size_t)cc * 128 * CH, CH, ws_, tid);
    __syncthreads();
    if (!xfLoaded) {
#pragma unroll
      for (int rt = 0; rt < 2; ++rt)
#pragma unroll
        for (int kt = 0; kt < 4; ++kt)
          xf[rt][kt] = *(const half8*)&xs[w * 32 + rt * 16 + l16][kt * 32 + quad * 8];
      xfLoaded = true;
    }
    mm2x8(xf, ws_, l16, quad, acc);
#pragma unroll
    for (int nt = 0; nt < 8; ++nt) {
      int col = cc * 128 + nt * 16 + l16;
      float bv = b1[col];
#pragma unroll
      for (int rt = 0; rt < 2; ++rt)
#pragma unroll
        for (int r = 0; r < 4; ++r) {
          int row = rowBase + w * 32 + rt * 16 + quad * 4 + r;
          hout[(size_t)row * FFD + col] = (_Float16)(gelu_(acc[rt][nt][r] + bv));
        }
    }
  }
}

// ---------------------------------------------------------------------------
// FFN part 2: v += h @ W2 + b2   (128-row tile)
// ---------------------------------------------------------------------------
__global__ __launch_bounds__(256)
void ffn2(const _Float16* __restrict__ h,
          const _Float16* __restrict__ wt2, const float* __restrict__ b2,
          float* __restrict__ vio)
{
  __shared__ alignas(16) _Float16 ws_[128][136];
  const int tid = threadIdx.x;
  const int lane = tid & 63;
  const int w = tid >> 6;
  const int quad = lane >> 4;
  const int l16 = lane & 15;
  const int rowBase = blockIdx.x * 128;

  f32x4 acc[2][8];
  const f32x4 fzero = {0.0f, 0.0f, 0.0f, 0.0f};
#pragma unroll
  for (int rt = 0; rt < 2; ++rt)
#pragma unroll
    for (int nt = 0; nt < 8; ++nt) acc[rt][nt] = fzero;

  for (int kc = 0; kc < 4; ++kc) {
    __syncthreads();
    stage_w(wt2 + kc * 128, FFD, ws_, tid);   // rows=cout(128), k-slice kc*128..+128
    __syncthreads();
#pragma unroll
    for (int kt = 0; kt < 4; ++kt) {
      half8 hf[2];
#pragma unroll
      for (int rt = 0; rt < 2; ++rt)
        hf[rt] = *(const half8*)(h + (size_t)(rowBase + w * 32 + rt * 16 + l16) * FFD + kc * 128 + kt * 32 + quad * 8);
#pragma unroll
      for (int nt = 0; nt < 8; ++nt) {
        half8 wf = *(const half8*)&ws_[nt * 16 + l16][kt * 32 + quad * 8];
#pragma unroll
        for (int rt = 0; rt < 2; ++rt)
          acc[rt][nt] = __builtin_amdgcn_mfma_f32_16x16x32_f16(hf[rt], wf, acc[rt][nt], 0, 0, 0);
      }
    }
  }
#pragma unroll
  for (int nt = 0; nt < 8; ++nt) {
    int col = nt * 16 + l16;
    float bv = b2[col];
#pragma unroll
    for (int rt = 0; rt < 2; ++rt)
#pragma unroll
      for (int r = 0; r < 4; ++r) {
        int row = rowBase + w * 32 + rt * 16 + quad * 4 + r;
        vio[(size_t)row * CH + col] += acc[rt][nt][r] + bv;
      }
  }
}

// ---------------------------------------------------------------------------
// final: s = v + transpose(v); e = s@decW + decb; write dense row (zeros + 12)
// ---------------------------------------------------------------------------
__global__ __launch_bounds__(256)
void decode_row(const float* __restrict__ vin, const int* __restrict__ tidx,
                const int* __restrict__ nbr, const float* __restrict__ decW,
                const float* __restrict__ decB, float* __restrict__ out)
{
  __shared__ float ev[KNN];
  __shared__ int nbr_s[KNN];
  const int n = blockIdx.x;
  const int tid = threadIdx.x;
  const int lane = tid & 63;
  const int w = tid >> 6;
  if (tid < KNN) nbr_s[tid] = nbr[n * KNN + tid];
  float dw1 = decW[lane], dw2 = decW[lane + 64];
  for (int k = w; k < KNN; k += 4) {
    int e = n * KNN + k;
    int ti = tidx[e];
    float s1 = vin[(size_t)e * CH + lane];
    float s2 = vin[(size_t)e * CH + 64 + lane];
    if (ti >= 0) {
      s1 += vin[(size_t)ti * CH + lane];
      s2 += vin[(size_t)ti * CH + 64 + lane];
    }
    float tot = wave_sum(s1 * dw1 + s2 * dw2);
    if (lane == 0) ev[k] = tot + decB[0];
  }
  __syncthreads();
  float4 z = make_float4(0.f, 0.f, 0.f, 0.f);
  float4* row = (float4*)(out + (size_t)n * NPTS);
  for (int idx = tid; idx < NPTS / 4; idx += 256) row[idx] = z;
  __syncthreads();
  if (tid < KNN) out[(size_t)n * NPTS + nbr_s[tid]] = ev[tid];
}

// ---------------------------------------------------------------------------
extern "C" void kernel_launch(void* const* d_in, const int* in_sizes, int n_in,
                              void* d_out, int out_size, void* d_ws, size_t ws_size,
                              hipStream_t stream)
{
  (void)in_sizes; (void)n_in; (void)out_size; (void)ws_size;
  const float* coords  = (const float*)d_in[0];
  const float* t_ln_g  = (const float*)d_in[1];
  const float* t_ln_b  = (const float*)d_in[2];
  const float* t_Wa    = (const float*)d_in[3];
  const float* t_ba    = (const float*)d_in[4];
  const float* t_Wga   = (const float*)d_in[5];
  const float* t_bga   = (const float*)d_in[6];
  const float* t_Wb    = (const float*)d_in[7];
  const float* t_bb    = (const float*)d_in[8];
  const float* t_Wgb   = (const float*)d_in[9];
  const float* t_bgb   = (const float*)d_in[10];
  const float* t_Wo    = (const float*)d_in[11];
  const float* t_bo    = (const float*)d_in[12];
  const float* t_Wgo   = (const float*)d_in[13];
  const float* t_bgo   = (const float*)d_in[14];
  const float* t_lno_g = (const float*)d_in[15];
  const float* t_lno_b = (const float*)d_in[16];
  const float* f_ln_g  = (const float*)d_in[17];
  const float* f_ln_b  = (const float*)d_in[18];
  const float* f_W1    = (const float*)d_in[19];
  const float* f_b1    = (const float*)d_in[20];
  const float* f_W2    = (const float*)d_in[21];
  const float* f_b2    = (const float*)d_in[22];
  const float* dec_W   = (const float*)d_in[23];
  const float* dec_b   = (const float*)d_in[24];

  const size_t NKC = (size_t)MEDGE * CH;   // 12,582,912
  char* ws = (char*)d_ws;
  float* v        = (float*)(ws);
  _Float16* kbuf  = (_Float16*)(ws + NKC * 4);   // LN'ed k, fp16 (25 MB region)
  int* nbr    = (int*)(ws + NKC * 8);
  int* tidx   = (int*)(ws + NKC * 8 + (size_t)MEDGE * 4);
  _Float16* wbase = (_Float16*)(ws + NKC * 8 + (size_t)MEDGE * 8);
  const size_t WTRI = (size_t)12 * CH * CH;
  _Float16* wA  = wbase;
  _Float16* wGA = wA  + WTRI;
  _Float16* wB  = wGA + WTRI;
  _Float16* wGB = wB  + WTRI;
  _Float16* wGO = wGB + WTRI;
  _Float16* wO  = wGO + WTRI;
  _Float16* w1  = wO  + WTRI;
  _Float16* w2  = w1  + (size_t)6 * FFD * CH;

  // scratch inside d_out (free until decode_row rewrites it)
  _Float16* abuf  = (_Float16*)d_out;
  _Float16* bbuf  = abuf + NKC;
  _Float16* gobuf = bbuf + NKC;
  _Float16* hbuf  = gobuf + NKC;   // [MEDGE][512] f16

  // weight prep (single launch)
  PrepArgs pa;
  pa.src[0] = t_Wa;  pa.dst[0] = wA;  pa.R[0] = CH;  pa.C[0] = CH; pa.total[0] = 12 * CH * CH;
  pa.src[1] = t_Wga; pa.dst[1] = wGA; pa.R[1] = CH;  pa.C[1] = CH; pa.total[1] = 12 * CH * CH;
  pa.src[2] = t_Wb;  pa.dst[2] = wB;  pa.R[2] = CH;  pa.C[2] = CH; pa.total[2] = 12 * CH * CH;
  pa.src[3] = t_Wgb; pa.dst[3] = wGB; pa.R[3] = CH;  pa.C[3] = CH; pa.total[3] = 12 * CH * CH;
  pa.src[4] = t_Wgo; pa.dst[4] = wGO; pa.R[4] = CH;  pa.C[4] = CH; pa.total[4] = 12 * CH * CH;
  pa.src[5] = t_Wo;  pa.dst[5] = wO;  pa.R[5] = CH;  pa.C[5] = CH; pa.total[5] = 12 * CH * CH;
  pa.src[6] = f_W1;  pa.dst[6] = w1;  pa.R[6] = CH;  pa.C[6] = FFD; pa.total[6] = 6 * CH * FFD;
  pa.src[7] = f_W2;  pa.dst[7] = w2;  pa.R[7] = FFD; pa.C[7] = CH;  pa.total[7] = 6 * FFD * CH;
  dim3 pgrid(1536, 8);
  prep_weights<<<pgrid, 256, 0, stream>>>(pa);

  knn_embed<<<NPTS, 256, 0, stream>>>(coords, nbr, v);
  build_tidx<<<MEDGE / 256, 256, 0, stream>>>(nbr, tidx);

  for (int l = 0; l < 6; ++l) {
    for (int rc = 0; rc < 2; ++rc) {
      int s = l * 2 + rc;
      ln_gemm5<<<MEDGE / 128, 256, 0, stream>>>(v,
          t_ln_g + s * CH, t_ln_b + s * CH,
          wA  + (size_t)s * CH * CH, t_ba  + s * CH,
          wGA + (size_t)s * CH * CH, t_bga + s * CH,
          wB  + (size_t)s * CH * CH, t_bb  + s * CH,
          wGB + (size_t)s * CH * CH, t_bgb + s * CH,
          wGO + (size_t)s * CH * CH, t_bgo + s * CH,
          abuf, bbuf, gobuf);
      tri_einsum_ln<<<NPTS, 256, 0, stream>>>(abuf, bbuf, nbr, tidx,
          t_lno_g + s * CH, t_lno_b + s * CH, kbuf, rc);
      out_gemm<<<MEDGE / 128, 256, 0, stream>>>(kbuf,
          wO + (size_t)s * CH * CH, t_bo + s * CH, gobuf, v);
    }
    ffn1<<<MEDGE / 128, 256, 0, stream>>>(v, f_ln_g + l * CH, f_ln_b + l * CH,
        w1 + (size_t)l * FFD * CH, f_b1 + l * FFD, hbuf);
    ffn2<<<MEDGE / 128, 256, 0, stream>>>(hbuf, w2 + (size_t)l * FFD * CH,
        f_b2 + l * CH, v);
  }

  decode_row<<<NPTS, 256, 0, stream>>>(v, tidx, nbr, dec_W, dec_b, (float*)d_out);
}

// Round 4
// 3812.511 us; speedup vs baseline: 1.2646x; 1.2646x over previous
//
#include <hip/hip_runtime.h>
#include <hip/hip_bf16.h>
#include <stdint.h>
#include <stddef.h>

#define NPTS 8192
#define KNN  12
#define CH   128
#define FFD  512
#define MEDGE (NPTS * KNN)   // 98304 edges

typedef __attribute__((ext_vector_type(8))) _Float16 half8;
typedef __attribute__((ext_vector_type(4))) _Float16 half4;
typedef __attribute__((ext_vector_type(4))) float f32x4;

__device__ __forceinline__ float wave_sum(float v) {
#pragma unroll
  for (int off = 32; off > 0; off >>= 1) v += __shfl_xor(v, off, 64);
  return v;
}
__device__ __forceinline__ float sigm_(float x) { return 1.0f / (1.0f + expf(-x)); }
__device__ __forceinline__ float gelu_(float x) { return 0.5f * x * (1.0f + erff(x * 0.7071067811865475f)); }

// ---------------------------------------------------------------------------
// coords -> float4-padded
// ---------------------------------------------------------------------------
__global__ __launch_bounds__(256)
void prep_coords(const float* __restrict__ c, float4* __restrict__ c4)
{
  int i = blockIdx.x * 256 + threadIdx.x;
  if (i < NPTS) c4[i] = make_float4(c[3 * i], c[3 * i + 1], c[3 * i + 2], 0.0f);
}

// ---------------------------------------------------------------------------
// weight swizzle to MFMA A-fragment chunk order:
// chunk c = ((mt*kts + kt)*4 + quad)*16 + l16 ; 8 halfs = W[b][kt*32+quad*8+e][mt*16+l16]
// ---------------------------------------------------------------------------
struct SwzArgs {
  const float* src[8];
  _Float16* dst[8];
  int K[8], N[8], B[8], perB[8];
};

__global__ __launch_bounds__(256)
void prep_weights_swz(SwzArgs sa)
{
  int g = blockIdx.y;
  int idx = blockIdx.x * 256 + threadIdx.x;
  int perB = sa.perB[g];
  if (idx >= sa.B[g] * perB) return;
  int K = sa.K[g], N = sa.N[g];
  int b = idx / perB;
  int c = idx - b * perB;
  int l16 = c & 15;
  int quad = (c >> 4) & 3;
  int rest = c >> 6;
  int kts = K >> 5;
  int kt = rest % kts;
  int mt = rest / kts;
  const float* sp = sa.src[g] + ((size_t)b * K + kt * 32 + quad * 8) * N + mt * 16 + l16;
  _Float16* dp = sa.dst[g] + ((size_t)b * perB + c) * 8;
#pragma unroll
  for (int e = 0; e < 8; ++e) dp[e] = (_Float16)sp[(size_t)e * N];
}

// ---------------------------------------------------------------------------
// KNN + RBF embed + fused LN(s=0) -> nbr, v0 f32, xln0 f16
// ---------------------------------------------------------------------------
__global__ __launch_bounds__(256)
void knn_embed(const float4* __restrict__ coords4, const float* __restrict__ lng,
               const float* __restrict__ lnb, int* __restrict__ nbr,
               float* __restrict__ v0, _Float16* __restrict__ xln)
{
#pragma clang fp contract(off)
  __shared__ unsigned long long wmin[4];
  __shared__ unsigned long long sel[KNN];
  const int i = blockIdx.x;
  const int tid = threadIdx.x;
  const int lane = tid & 63;
  const int wv = tid >> 6;
  const float4 ci = coords4[i];
  unsigned long long best[KNN];
#pragma unroll
  for (int q = 0; q < KNN; ++q) best[q] = ~0ULL;
  for (int j = tid; j < NPTS; j += 256) {
    float4 cj = coords4[j];
    float dx = ci.x - cj.x;
    float dy = ci.y - cj.y;
    float dz = ci.z - cj.z;
    float d2 = dx * dx + dy * dy + dz * dz;   // contract off: matches numpy
    float d = sqrtf(d2);
    unsigned long long key = (((unsigned long long)__float_as_uint(d)) << 32) | (unsigned int)j;
    if (key < best[KNN - 1]) {
      best[KNN - 1] = key;
#pragma unroll
      for (int q = KNN - 2; q >= 0; --q) {
        if (best[q + 1] < best[q]) { unsigned long long t = best[q]; best[q] = best[q + 1]; best[q + 1] = t; }
      }
    }
  }
  int p = 0;
  for (int r = 0; r < KNN; ++r) {
    unsigned long long c = ~0ULL;
#pragma unroll
    for (int q = 0; q < KNN; ++q) if (q == p) c = best[q];
    unsigned long long m = c;
#pragma unroll
    for (int off = 32; off > 0; off >>= 1) {
      unsigned long long o = __shfl_xor(m, off, 64);
      if (o < m) m = o;
    }
    if (lane == 0) wmin[wv] = m;
    __syncthreads();
    unsigned long long g = wmin[0];
    if (wmin[1] < g) g = wmin[1];
    if (wmin[2] < g) g = wmin[2];
    if (wmin[3] < g) g = wmin[3];
    if (c == g) ++p;
    if (tid == 0) sel[r] = g;
    __syncthreads();
  }
  if (tid < KNN) nbr[i * KNN + tid] = (int)(unsigned int)(sel[tid] & 0xFFFFFFFFULL);
  // embed + LN per row (3 rows per wave)
  float g1 = lng[lane], g2 = lng[lane + 64];
  float bb1 = lnb[lane], bb2 = lnb[lane + 64];
  for (int k = wv * 3; k < wv * 3 + 3; ++k) {
    float d = __uint_as_float((unsigned int)(sel[k] >> 32));
    float sig1 = (float)(1.0 + 4.0 * (double)lane / 127.0);
    float sig2 = (float)(1.0 + 4.0 * (double)(lane + 64) / 127.0);
    float e1 = expf((-(d * d)) / (2.0f * sig1 * sig1));
    float e2 = expf((-(d * d)) / (2.0f * sig2 * sig2));
    float v1 = (e1 > 0.1f) ? e1 : 0.0f;
    float v2 = (e2 > 0.1f) ? e2 : 0.0f;
    size_t off = (size_t)(i * KNN + k) * CH;
    v0[off + lane] = v1;
    v0[off + lane + 64] = v2;
    float m = wave_sum(v1 + v2) * (1.0f / 128.0f);
    float d1 = v1 - m, d2 = v2 - m;
    float var = wave_sum(d1 * d1 + d2 * d2) * (1.0f / 128.0f);
    float rs = 1.0f / sqrtf(var + 1e-5f);
    xln[off + lane]      = (_Float16)(d1 * rs * g1 + bb1);
    xln[off + lane + 64] = (_Float16)(d2 * rs * g2 + bb2);
  }
}

// ---------------------------------------------------------------------------
__global__ __launch_bounds__(256)
void build_tidx(const int* __restrict__ nbr, int* __restrict__ tidx)
{
  int e = blockIdx.x * 256 + threadIdx.x;
  if (e >= MEDGE) return;
  int i = e / KNN;
  int j = nbr[e];
  int res = -1;
#pragma unroll
  for (int t = 0; t < KNN; ++t) {
    if (nbr[j * KNN + t] == i) { res = j * KNN + t; break; }
  }
  tidx[e] = res;
}

// ---------------------------------------------------------------------------
// a = sig(x@Wga+bga)*(x@Wa+ba), b likewise.  Streaming, no LDS, rt=2.
// mfma(wf, xf): D rows=couts(quad*4+r within mt*16), cols=x-rows(l16).
// ---------------------------------------------------------------------------
__global__ __launch_bounds__(256)
void gemm_ab(const _Float16* __restrict__ xln,
             const _Float16* __restrict__ wa,  const float* __restrict__ ba,
             const _Float16* __restrict__ wga, const float* __restrict__ bga,
             const _Float16* __restrict__ wb,  const float* __restrict__ bb,
             const _Float16* __restrict__ wgb, const float* __restrict__ bgb,
             _Float16* __restrict__ aout, _Float16* __restrict__ bout)
{
  const int lane = threadIdx.x & 63;
  const int quad = lane >> 4;
  const int l16 = lane & 15;
  const int gw = blockIdx.x * 4 + (threadIdx.x >> 6);
  const int base = gw * 32;
  const int chbase = quad * 16 + l16;

  half8 xf[2][4];
#pragma unroll
  for (int rt = 0; rt < 2; ++rt)
#pragma unroll
    for (int kt = 0; kt < 4; ++kt)
      xf[rt][kt] = *(const half8*)(xln + (size_t)(base + rt * 16 + l16) * CH + kt * 32 + quad * 8);

  const half8* WA  = (const half8*)wa;
  const half8* WGA = (const half8*)wga;
  const half8* WB  = (const half8*)wb;
  const half8* WGB = (const half8*)wgb;

#pragma unroll
  for (int mt = 0; mt < 8; ++mt) {
    f32x4 aA[2], aGA[2], aB[2], aGB[2];
    const f32x4 z = {0.f, 0.f, 0.f, 0.f};
#pragma unroll
    for (int rt = 0; rt < 2; ++rt) { aA[rt] = z; aGA[rt] = z; aB[rt] = z; aGB[rt] = z; }
#pragma unroll
    for (int kt = 0; kt < 4; ++kt) {
      int ch = (mt * 4 + kt) * 64 + chbase;
      half8 wfa = WA[ch], wfga = WGA[ch], wfb = WB[ch], wfgb = WGB[ch];
#pragma unroll
      for (int rt = 0; rt < 2; ++rt) {
        aA[rt]  = __builtin_amdgcn_mfma_f32_16x16x32_f16(wfa,  xf[rt][kt], aA[rt], 0, 0, 0);
        aGA[rt] = __builtin_amdgcn_mfma_f32_16x16x32_f16(wfga, xf[rt][kt], aGA[rt], 0, 0, 0);
        aB[rt]  = __builtin_amdgcn_mfma_f32_16x16x32_f16(wfb,  xf[rt][kt], aB[rt], 0, 0, 0);
        aGB[rt] = __builtin_amdgcn_mfma_f32_16x16x32_f16(wfgb, xf[rt][kt], aGB[rt], 0, 0, 0);
      }
    }
    f32x4 bva  = *(const f32x4*)(ba  + mt * 16 + quad * 4);
    f32x4 bvga = *(const f32x4*)(bga + mt * 16 + quad * 4);
    f32x4 bvb  = *(const f32x4*)(bb  + mt * 16 + quad * 4);
    f32x4 bvgb = *(const f32x4*)(bgb + mt * 16 + quad * 4);
#pragma unroll
    for (int rt = 0; rt < 2; ++rt) {
      half4 av, bv;
#pragma unroll
      for (int r = 0; r < 4; ++r) {
        av[r] = (_Float16)(sigm_(aGA[rt][r] + bvga[r]) * (aA[rt][r] + bva[r]));
        bv[r] = (_Float16)(sigm_(aGB[rt][r] + bvgb[r]) * (aB[rt][r] + bvb[r]));
      }
      size_t off = (size_t)(base + rt * 16 + l16) * CH + mt * 16 + quad * 4;
      *(half4*)(aout + off) = av;
      *(half4*)(bout + off) = bv;
    }
  }
}

// ---------------------------------------------------------------------------
// sparse triangle einsum + fused LN -> kln f16
// ---------------------------------------------------------------------------
__global__ __launch_bounds__(256)
void tri_einsum_ln(const _Float16* __restrict__ a, const _Float16* __restrict__ b,
                   const int* __restrict__ nbr, const int* __restrict__ tidx,
                   const float* __restrict__ lng, const float* __restrict__ lnb,
                   _Float16* __restrict__ kout, int incoming)
{
  __shared__ float As[KNN][CH];
  __shared__ int bidx[KNN][KNN];
  __shared__ int nbr_s[KNN];
  __shared__ float part[6][4][2];
  const int n = blockIdx.x;
  const int tid = threadIdx.x;
  const int wv = tid >> 6;
  if (tid < KNN) nbr_s[tid] = nbr[n * KNN + tid];
  __syncthreads();
  if (tid < KNN * KNN) {
    int m = tid / KNN, t = tid - m * KNN;
    int j = nbr_s[m];
    bidx[m][t] = incoming ? tidx[j * KNN + t] : (j * KNN + t);
  }
  for (int idx = tid; idx < KNN * CH; idx += 256) {
    int t = idx >> 7, c = idx & 127;
    float av;
    if (incoming) {
      int ti = tidx[n * KNN + t];
      av = (ti >= 0) ? (float)(a[(size_t)ti * CH + c]) : 0.0f;
    } else {
      av = (float)(a[(size_t)(n * KNN + t) * CH + c]);
    }
    As[t][c] = av;
  }
  __syncthreads();
  const int c = tid & 127;
  const int mh = tid >> 7;
  const float gc = lng[c], bc = lnb[c];
  for (int mm = 0; mm < 6; ++mm) {
    int m = mm * 2 + mh;
    float acc = 0.0f;
#pragma unroll
    for (int t = 0; t < KNN; ++t) {
      int bi = bidx[m][t];
      float bv = (bi >= 0) ? (float)(b[(size_t)bi * CH + c]) : 0.0f;
      acc += As[t][c] * bv;
    }
    float s1 = wave_sum(acc);
    float s2 = wave_sum(acc * acc);
    if ((tid & 63) == 0) { part[mm][wv][0] = s1; part[mm][wv][1] = s2; }
    __syncthreads();
    int pb = mh * 2;
    float sum = part[mm][pb][0] + part[mm][pb + 1][0];
    float sq  = part[mm][pb][1] + part[mm][pb + 1][1];
    float mean = sum * (1.0f / 128.0f);
    float var = sq * (1.0f / 128.0f) - mean * mean;
    if (var < 0.0f) var = 0.0f;
    float rs = 1.0f / sqrtf(var + 1e-5f);
    kout[(size_t)(n * KNN + m) * CH + c] = (_Float16)((acc - mean) * rs * gc + bc);
  }
}

// ---------------------------------------------------------------------------
// v += sig(x@Wgo+bgo) * (kln@Wo + bo);  xln_next = LN(v)*g+b.  rt=1 streaming.
// ---------------------------------------------------------------------------
__global__ __launch_bounds__(256)
void out_go_gemm(const _Float16* __restrict__ kln,
                 const _Float16* __restrict__ wo,  const float* __restrict__ bo,
                 const _Float16* __restrict__ xln,
                 const _Float16* __restrict__ wgo, const float* __restrict__ bgo,
                 float* __restrict__ v,
                 const float* __restrict__ nlng, const float* __restrict__ nlnb,
                 _Float16* __restrict__ xlnN)
{
  const int lane = threadIdx.x & 63;
  const int quad = lane >> 4;
  const int l16 = lane & 15;
  const int gw = blockIdx.x * 4 + (threadIdx.x >> 6);
  const int base = gw * 16;
  const int chbase = quad * 16 + l16;
  const size_t rowOff = (size_t)(base + l16) * CH;

  half8 kf[4], xf[4];
#pragma unroll
  for (int kt = 0; kt < 4; ++kt) {
    kf[kt] = *(const half8*)(kln + rowOff + kt * 32 + quad * 8);
    xf[kt] = *(const half8*)(xln + rowOff + kt * 32 + quad * 8);
  }
  const half8* WO  = (const half8*)wo;
  const half8* WGO = (const half8*)wgo;

  f32x4 vn[8];
  float s = 0.0f, sq = 0.0f;
#pragma unroll
  for (int mt = 0; mt < 8; ++mt) {
    f32x4 aO = {0.f, 0.f, 0.f, 0.f}, aG = {0.f, 0.f, 0.f, 0.f};
#pragma unroll
    for (int kt = 0; kt < 4; ++kt) {
      int ch = (mt * 4 + kt) * 64 + chbase;
      aO = __builtin_amdgcn_mfma_f32_16x16x32_f16(WO[ch],  kf[kt], aO, 0, 0, 0);
      aG = __builtin_amdgcn_mfma_f32_16x16x32_f16(WGO[ch], xf[kt], aG, 0, 0, 0);
    }
    f32x4 bvo = *(const f32x4*)(bo  + mt * 16 + quad * 4);
    f32x4 bvg = *(const f32x4*)(bgo + mt * 16 + quad * 4);
    f32x4 vv = *(const f32x4*)(v + rowOff + mt * 16 + quad * 4);
#pragma unroll
    for (int r = 0; r < 4; ++r) {
      float nv = vv[r] + sigm_(aG[r] + bvg[r]) * (aO[r] + bvo[r]);
      vn[mt][r] = nv;
      s += nv;
      sq += nv * nv;
    }
    *(f32x4*)(v + rowOff + mt * 16 + quad * 4) = vn[mt];
  }
  s  += __shfl_xor(s, 16, 64);  s  += __shfl_xor(s, 32, 64);
  sq += __shfl_xor(sq, 16, 64); sq += __shfl_xor(sq, 32, 64);
  float mean = s * (1.0f / 128.0f);
  float var = sq * (1.0f / 128.0f) - mean * mean;
  if (var < 0.0f) var = 0.0f;
  float rs = 1.0f / sqrtf(var + 1e-5f);
#pragma unroll
  for (int mt = 0; mt < 8; ++mt) {
    f32x4 g4 = *(const f32x4*)(nlng + mt * 16 + quad * 4);
    f32x4 b4 = *(const f32x4*)(nlnb + mt * 16 + quad * 4);
    half4 o;
#pragma unroll
    for (int r = 0; r < 4; ++r)
      o[r] = (_Float16)((vn[mt][r] - mean) * rs * g4[r] + b4[r]);
    *(half4*)(xlnN + rowOff + mt * 16 + quad * 4) = o;
  }
}

// ---------------------------------------------------------------------------
// h = gelu(x@W1 + b1)  [M,512] f16.  rt=2 streaming.
// ---------------------------------------------------------------------------
__global__ __launch_bounds__(256)
void ffn1(const _Float16* __restrict__ xln,
          const _Float16* __restrict__ w1, const float* __restrict__ b1,
          _Float16* __restrict__ hout)
{
  const int lane = threadIdx.x & 63;
  const int quad = lane >> 4;
  const int l16 = lane & 15;
  const int gw = blockIdx.x * 4 + (threadIdx.x >> 6);
  const int base = gw * 32;
  const int chbase = quad * 16 + l16;

  half8 xf[2][4];
#pragma unroll
  for (int rt = 0; rt < 2; ++rt)
#pragma unroll
    for (int kt = 0; kt < 4; ++kt)
      xf[rt][kt] = *(const half8*)(xln + (size_t)(base + rt * 16 + l16) * CH + kt * 32 + quad * 8);

  const half8* W1 = (const half8*)w1;
#pragma unroll
  for (int mt = 0; mt < 32; ++mt) {
    f32x4 acc[2];
    const f32x4 z = {0.f, 0.f, 0.f, 0.f};
    acc[0] = z; acc[1] = z;
#pragma unroll
    for (int kt = 0; kt < 4; ++kt) {
      half8 wf = W1[(mt * 4 + kt) * 64 + chbase];
#pragma unroll
      for (int rt = 0; rt < 2; ++rt)
        acc[rt] = __builtin_amdgcn_mfma_f32_16x16x32_f16(wf, xf[rt][kt], acc[rt], 0, 0, 0);
    }
    f32x4 bv = *(const f32x4*)(b1 + mt * 16 + quad * 4);
#pragma unroll
    for (int rt = 0; rt < 2; ++rt) {
      half4 hh;
#pragma unroll
      for (int r = 0; r < 4; ++r)
        hh[r] = (_Float16)(gelu_(acc[rt][r] + bv[r]));
      *(half4*)(hout + (size_t)(base + rt * 16 + l16) * FFD + mt * 16 + quad * 4) = hh;
    }
  }
}

// ---------------------------------------------------------------------------
// v += h@W2 + b2;  xln_next = LN(v)*g+b.  rt=1 streaming, k=512.
// ---------------------------------------------------------------------------
__global__ __launch_bounds__(256)
void ffn2(const _Float16* __restrict__ h,
          const _Float16* __restrict__ w2, const float* __restrict__ b2,
          float* __restrict__ v,
          const float* __restrict__ nlng, const float* __restrict__ nlnb,
          _Float16* __restrict__ xlnN)
{
  const int lane = threadIdx.x & 63;
  const int quad = lane >> 4;
  const int l16 = lane & 15;
  const int gw = blockIdx.x * 4 + (threadIdx.x >> 6);
  const int base = gw * 16;
  const int chbase = quad * 16 + l16;
  const size_t rowOff = (size_t)(base + l16) * CH;
  const size_t hOff = (size_t)(base + l16) * FFD;

  half8 hf[16];
#pragma unroll
  for (int kt = 0; kt < 16; ++kt)
    hf[kt] = *(const half8*)(h + hOff + kt * 32 + quad * 8);

  const half8* W2 = (const half8*)w2;
  f32x4 vn[8];
  float s = 0.0f, sq = 0.0f;
#pragma unroll
  for (int mt = 0; mt < 8; ++mt) {
    f32x4 acc = {0.f, 0.f, 0.f, 0.f};
#pragma unroll
    for (int kt = 0; kt < 16; ++kt)
      acc = __builtin_amdgcn_mfma_f32_16x16x32_f16(W2[(mt * 16 + kt) * 64 + chbase], hf[kt], acc, 0, 0, 0);
    f32x4 bv = *(const f32x4*)(b2 + mt * 16 + quad * 4);
    f32x4 vv = *(const f32x4*)(v + rowOff + mt * 16 + quad * 4);
#pragma unroll
    for (int r = 0; r < 4; ++r) {
      float nv = vv[r] + acc[r] + bv[r];
      vn[mt][r] = nv;
      s += nv;
      sq += nv * nv;
    }
    *(f32x4*)(v + rowOff + mt * 16 + quad * 4) = vn[mt];
  }
  s  += __shfl_xor(s, 16, 64);  s  += __shfl_xor(s, 32, 64);
  sq += __shfl_xor(sq, 16, 64); sq += __shfl_xor(sq, 32, 64);
  float mean = s * (1.0f / 128.0f);
  float var = sq * (1.0f / 128.0f) - mean * mean;
  if (var < 0.0f) var = 0.0f;
  float rs = 1.0f / sqrtf(var + 1e-5f);
#pragma unroll
  for (int mt = 0; mt < 8; ++mt) {
    f32x4 g4 = *(const f32x4*)(nlng + mt * 16 + quad * 4);
    f32x4 b4 = *(const f32x4*)(nlnb + mt * 16 + quad * 4);
    half4 o;
#pragma unroll
    for (int r = 0; r < 4; ++r)
      o[r] = (_Float16)((vn[mt][r] - mean) * rs * g4[r] + b4[r]);
    *(half4*)(xlnN + rowOff + mt * 16 + quad * 4) = o;
  }
}

// ---------------------------------------------------------------------------
// final: s = v + transpose(v); e = s@decW + decb; write dense row
// ---------------------------------------------------------------------------
__global__ __launch_bounds__(256)
void decode_row(const float* __restrict__ vin, const int* __restrict__ tidx,
                const int* __restrict__ nbr, const float* __restrict__ decW,
                const float* __restrict__ decB, float* __restrict__ out)
{
  __shared__ float ev[KNN];
  __shared__ int nbr_s[KNN];
  const int n = blockIdx.x;
  const int tid = threadIdx.x;
  const int lane = tid & 63;
  const int w = tid >> 6;
  if (tid < KNN) nbr_s[tid] = nbr[n * KNN + tid];
  float dw1 = decW[lane], dw2 = decW[lane + 64];
  for (int k = w; k < KNN; k += 4) {
    int e = n * KNN + k;
    int ti = tidx[e];
    float s1 = vin[(size_t)e * CH + lane];
    float s2 = vin[(size_t)e * CH + 64 + lane];
    if (ti >= 0) {
      s1 += vin[(size_t)ti * CH + lane];
      s2 += vin[(size_t)ti * CH + 64 + lane];
    }
    float tot = wave_sum(s1 * dw1 + s2 * dw2);
    if (lane == 0) ev[k] = tot + decB[0];
  }
  __syncthreads();
  float4 z = make_float4(0.f, 0.f, 0.f, 0.f);
  float4* row = (float4*)(out + (size_t)n * NPTS);
  for (int idx = tid; idx < NPTS / 4; idx += 256) row[idx] = z;
  __syncthreads();
  if (tid < KNN) out[(size_t)n * NPTS + nbr_s[tid]] = ev[tid];
}

// ---------------------------------------------------------------------------
extern "C" void kernel_launch(void* const* d_in, const int* in_sizes, int n_in,
                              void* d_out, int out_size, void* d_ws, size_t ws_size,
                              hipStream_t stream)
{
  (void)in_sizes; (void)n_in; (void)out_size; (void)ws_size;
  const float* coords  = (const float*)d_in[0];
  const float* t_ln_g  = (const float*)d_in[1];
  const float* t_ln_b  = (const float*)d_in[2];
  const float* t_Wa    = (const float*)d_in[3];
  const float* t_ba    = (const float*)d_in[4];
  const float* t_Wga   = (const float*)d_in[5];
  const float* t_bga   = (const float*)d_in[6];
  const float* t_Wb    = (const float*)d_in[7];
  const float* t_bb    = (const float*)d_in[8];
  const float* t_Wgb   = (const float*)d_in[9];
  const float* t_bgb   = (const float*)d_in[10];
  const float* t_Wo    = (const float*)d_in[11];
  const float* t_bo    = (const float*)d_in[12];
  const float* t_Wgo   = (const float*)d_in[13];
  const float* t_bgo   = (const float*)d_in[14];
  const float* t_lno_g = (const float*)d_in[15];
  const float* t_lno_b = (const float*)d_in[16];
  const float* f_ln_g  = (const float*)d_in[17];
  const float* f_ln_b  = (const float*)d_in[18];
  const float* f_W1    = (const float*)d_in[19];
  const float* f_b1    = (const float*)d_in[20];
  const float* f_W2    = (const float*)d_in[21];
  const float* f_b2    = (const float*)d_in[22];
  const float* dec_W   = (const float*)d_in[23];
  const float* dec_b   = (const float*)d_in[24];

  const size_t NKC = (size_t)MEDGE * CH;   // 12,582,912
  char* ws = (char*)d_ws;
  float* v        = (float*)(ws);                       // 50.3 MB
  _Float16* kln   = (_Float16*)(ws + NKC * 4);          // 25.2 MB
  _Float16* xln   = (_Float16*)(ws + NKC * 6);          // 25.2 MB
  int* nbr        = (int*)(ws + NKC * 8);
  int* tidx       = (int*)(ws + NKC * 8 + (size_t)MEDGE * 4);
  float4* coords4 = (float4*)(ws + NKC * 8 + (size_t)MEDGE * 8);
  _Float16* wbase = (_Float16*)(ws + NKC * 8 + (size_t)MEDGE * 8 + NPTS * 16);
  const size_t TRIH = (size_t)12 * 2048 * 8;   // halfs per tri weight tensor
  _Float16* wA  = wbase;
  _Float16* wGA = wA  + TRIH;
  _Float16* wB  = wGA + TRIH;
  _Float16* wGB = wB  + TRIH;
  _Float16* wGO = wGB + TRIH;
  _Float16* wO  = wGO + TRIH;
  _Float16* w1  = wO  + TRIH;                  // 6 * 8192 * 8 halfs
  _Float16* w2  = w1  + (size_t)6 * 8192 * 8;

  // scratch inside d_out (free until decode_row)
  _Float16* abuf = (_Float16*)d_out;
  _Float16* bbuf = abuf + NKC;
  _Float16* hbuf = bbuf + NKC;   // [MEDGE][512] f16

  prep_coords<<<32, 256, 0, stream>>>(coords, coords4);

  SwzArgs sa;
  sa.src[0] = t_Wa;  sa.dst[0] = wA;  sa.K[0] = CH;  sa.N[0] = CH;  sa.B[0] = 12; sa.perB[0] = 2048;
  sa.src[1] = t_Wga; sa.dst[1] = wGA; sa.K[1] = CH;  sa.N[1] = CH;  sa.B[1] = 12; sa.perB[1] = 2048;
  sa.src[2] = t_Wb;  sa.dst[2] = wB;  sa.K[2] = CH;  sa.N[2] = CH;  sa.B[2] = 12; sa.perB[2] = 2048;
  sa.src[3] = t_Wgb; sa.dst[3] = wGB; sa.K[3] = CH;  sa.N[3] = CH;  sa.B[3] = 12; sa.perB[3] = 2048;
  sa.src[4] = t_Wgo; sa.dst[4] = wGO; sa.K[4] = CH;  sa.N[4] = CH;  sa.B[4] = 12; sa.perB[4] = 2048;
  sa.src[5] = t_Wo;  sa.dst[5] = wO;  sa.K[5] = CH;  sa.N[5] = CH;  sa.B[5] = 12; sa.perB[5] = 2048;
  sa.src[6] = f_W1;  sa.dst[6] = w1;  sa.K[6] = CH;  sa.N[6] = FFD; sa.B[6] = 6;  sa.perB[6] = 8192;
  sa.src[7] = f_W2;  sa.dst[7] = w2;  sa.K[7] = FFD; sa.N[7] = CH;  sa.B[7] = 6;  sa.perB[7] = 8192;
  dim3 pgrid(192, 8);
  prep_weights_swz<<<pgrid, 256, 0, stream>>>(sa);

  knn_embed<<<NPTS, 256, 0, stream>>>(coords4, t_ln_g, t_ln_b, nbr, v, xln);
  build_tidx<<<MEDGE / 256, 256, 0, stream>>>(nbr, tidx);

  const int G32 = MEDGE / (4 * 32);   // 768 blocks (rt=2)
  const int G16 = MEDGE / (4 * 16);   // 1536 blocks (rt=1)

  for (int l = 0; l < 6; ++l) {
    for (int rc = 0; rc < 2; ++rc) {
      int s = l * 2 + rc;
      gemm_ab<<<G32, 256, 0, stream>>>(xln,
          wA  + (size_t)s * 2048 * 8, t_ba  + s * CH,
          wGA + (size_t)s * 2048 * 8, t_bga + s * CH,
          wB  + (size_t)s * 2048 * 8, t_bb  + s * CH,
          wGB + (size_t)s * 2048 * 8, t_bgb + s * CH,
          abuf, bbuf);
      tri_einsum_ln<<<NPTS, 256, 0, stream>>>(abuf, bbuf, nbr, tidx,
          t_lno_g + s * CH, t_lno_b + s * CH, kln, rc);
      // next-LN params: rc=0 -> tri s+1 ; rc=1 -> ffn layer l
      const float* ng = (rc == 0) ? (t_ln_g + (s + 1) * CH) : (f_ln_g + l * CH);
      const float* nb = (rc == 0) ? (t_ln_b + (s + 1) * CH) : (f_ln_b + l * CH);
      out_go_gemm<<<G16, 256, 0, stream>>>(kln,
          wO  + (size_t)s * 2048 * 8, t_bo  + s * CH,
          xln,
          wGO + (size_t)s * 2048 * 8, t_bgo + s * CH,
          v, ng, nb, xln);
    }
    ffn1<<<G32, 256, 0, stream>>>(xln, w1 + (size_t)l * 8192 * 8, f_b1 + l * FFD, hbuf);
    // next-LN params: tri s=(l+1)*2 (last layer: dummy, unused)
    const float* ng = (l < 5) ? (t_ln_g + (l + 1) * 2 * CH) : t_ln_g;
    const float* nb = (l < 5) ? (t_ln_b + (l + 1) * 2 * CH) : t_ln_b;
    ffn2<<<G16, 256, 0, stream>>>(hbuf, w2 + (size_t)l * 8192 * 8, f_b2 + l * CH,
        v, ng, nb, xln);
  }

  decode_row<<<NPTS, 256, 0, stream>>>(v, tidx, nbr, dec_W, dec_b, (float*)d_out);
}

// Round 5
// 3362.384 us; speedup vs baseline: 1.4339x; 1.1339x over previous
//
#include <hip/hip_runtime.h>
#include <hip/hip_bf16.h>
#include <stdint.h>
#include <stddef.h>

#define NPTS 8192
#define KNN  12
#define CH   128
#define FFD  512
#define MEDGE (NPTS * KNN)   // 98304 edges

typedef __attribute__((ext_vector_type(8))) _Float16 half8;
typedef __attribute__((ext_vector_type(4))) _Float16 half4;
typedef __attribute__((ext_vector_type(4))) float f32x4;

__device__ __forceinline__ float wave_sum(float v) {
#pragma unroll
  for (int off = 32; off > 0; off >>= 1) v += __shfl_xor(v, off, 64);
  return v;
}
__device__ __forceinline__ float sigm_(float x) { return 1.0f / (1.0f + expf(-x)); }
__device__ __forceinline__ float gelu_(float x) { return 0.5f * x * (1.0f + erff(x * 0.7071067811865475f)); }

// ---------------------------------------------------------------------------
// coords -> float4-padded
// ---------------------------------------------------------------------------
__global__ __launch_bounds__(256)
void prep_coords(const float* __restrict__ c, float4* __restrict__ c4)
{
  int i = blockIdx.x * 256 + threadIdx.x;
  if (i < NPTS) c4[i] = make_float4(c[3 * i], c[3 * i + 1], c[3 * i + 2], 0.0f);
}

// ---------------------------------------------------------------------------
// weight swizzle to MFMA A-fragment chunk order:
// chunk c = ((mt*kts + kt)*4 + quad)*16 + l16 ; 8 halfs = W[b][kt*32+quad*8+e][mt*16+l16]
// ---------------------------------------------------------------------------
struct SwzArgs {
  const float* src[8];
  _Float16* dst[8];
  int K[8], N[8], B[8], perB[8];
};

__global__ __launch_bounds__(256)
void prep_weights_swz(SwzArgs sa)
{
  int g = blockIdx.y;
  int idx = blockIdx.x * 256 + threadIdx.x;
  int perB = sa.perB[g];
  if (idx >= sa.B[g] * perB) return;
  int K = sa.K[g], N = sa.N[g];
  int b = idx / perB;
  int c = idx - b * perB;
  int l16 = c & 15;
  int quad = (c >> 4) & 3;
  int rest = c >> 6;
  int kts = K >> 5;
  int kt = rest % kts;
  int mt = rest / kts;
  const float* sp = sa.src[g] + ((size_t)b * K + kt * 32 + quad * 8) * N + mt * 16 + l16;
  _Float16* dp = sa.dst[g] + ((size_t)b * perB + c) * 8;
#pragma unroll
  for (int e = 0; e < 8; ++e) dp[e] = (_Float16)sp[(size_t)e * N];
}

// ---------------------------------------------------------------------------
// KNN via threshold filter: scan d2<T2 -> LDS buffer -> one-wave top-12 sort.
// Keys identical to full-sort version: (f32bits(sqrt(d2))<<32)|j
// ---------------------------------------------------------------------------
#define KNN_CAP 2048

__global__ __launch_bounds__(256)
void knn_embed(const float4* __restrict__ coords4, const float* __restrict__ lng,
               const float* __restrict__ lnb, int* __restrict__ nbr,
               float* __restrict__ v0, _Float16* __restrict__ xln)
{
#pragma clang fp contract(off)
  __shared__ unsigned long long buf[KNN_CAP];
  __shared__ unsigned long long sel[KNN];
  __shared__ int cnt_s;
  const int i = blockIdx.x;
  const int tid = threadIdx.x;
  const int lane = tid & 63;
  const int wv = tid >> 6;
  const float4 ci = coords4[i];

  float T2 = 9.0f;             // d < 3.0 first pass; ~60 passers interior
  int cnt;
  while (true) {
    if (tid == 0) cnt_s = 0;
    __syncthreads();
    for (int j = tid; j < NPTS; j += 256) {
      float4 cj = coords4[j];
      float dx = ci.x - cj.x;
      float dy = ci.y - cj.y;
      float dz = ci.z - cj.z;
      float d2 = dx * dx + dy * dy + dz * dz;   // contract off: matches numpy
      if (d2 < T2) {
        unsigned long long key =
            (((unsigned long long)__float_as_uint(sqrtf(d2))) << 32) | (unsigned int)j;
        int idx = atomicAdd(&cnt_s, 1);
        if (idx < KNN_CAP) buf[idx] = key;
      }
    }
    __syncthreads();
    cnt = cnt_s;
    if (cnt >= KNN) break;     // 12th-smallest d is < T, buffer is a superset
    T2 *= 4.0f;                // corner/edge points: widen and rescan (rare)
    __syncthreads();           // all reads of cnt_s done before reset
  }
  if (cnt > KNN_CAP) cnt = KNN_CAP;   // unreachable for uniform inputs

  if (wv == 0) {
    unsigned long long best[KNN];
#pragma unroll
    for (int q = 0; q < KNN; ++q) best[q] = ~0ULL;
    for (int p2 = lane; p2 < cnt; p2 += 64) {
      unsigned long long key = buf[p2];
      if (key < best[KNN - 1]) {
        best[KNN - 1] = key;
#pragma unroll
        for (int q = KNN - 2; q >= 0; --q) {
          if (best[q + 1] < best[q]) { unsigned long long t = best[q]; best[q] = best[q + 1]; best[q + 1] = t; }
        }
      }
    }
    int p = 0;
    for (int r = 0; r < KNN; ++r) {
      unsigned long long c = ~0ULL;
#pragma unroll
      for (int q = 0; q < KNN; ++q) if (q == p) c = best[q];
      unsigned long long m = c;
#pragma unroll
      for (int off = 32; off > 0; off >>= 1) {
        unsigned long long o = __shfl_xor(m, off, 64);
        if (o < m) m = o;
      }
      if (c == m) ++p;         // keys unique -> exactly one popper
      if (lane == 0) sel[r] = m;
    }
  }
  __syncthreads();
  if (tid < KNN) nbr[i * KNN + tid] = (int)(unsigned int)(sel[tid] & 0xFFFFFFFFULL);

  // embed + LN per row (3 rows per wave)
  float g1 = lng[lane], g2 = lng[lane + 64];
  float bb1 = lnb[lane], bb2 = lnb[lane + 64];
  for (int k = wv * 3; k < wv * 3 + 3; ++k) {
    float d = __uint_as_float((unsigned int)(sel[k] >> 32));
    float sig1 = (float)(1.0 + 4.0 * (double)lane / 127.0);
    float sig2 = (float)(1.0 + 4.0 * (double)(lane + 64) / 127.0);
    float e1 = expf((-(d * d)) / (2.0f * sig1 * sig1));
    float e2 = expf((-(d * d)) / (2.0f * sig2 * sig2));
    float v1 = (e1 > 0.1f) ? e1 : 0.0f;
    float v2 = (e2 > 0.1f) ? e2 : 0.0f;
    size_t off = (size_t)(i * KNN + k) * CH;
    v0[off + lane] = v1;
    v0[off + lane + 64] = v2;
    float m = wave_sum(v1 + v2) * (1.0f / 128.0f);
    float d1 = v1 - m, d2 = v2 - m;
    float var = wave_sum(d1 * d1 + d2 * d2) * (1.0f / 128.0f);
    float rs = 1.0f / sqrtf(var + 1e-5f);
    xln[off + lane]      = (_Float16)(d1 * rs * g1 + bb1);
    xln[off + lane + 64] = (_Float16)(d2 * rs * g2 + bb2);
  }
}

// ---------------------------------------------------------------------------
__global__ __launch_bounds__(256)
void build_tidx(const int* __restrict__ nbr, int* __restrict__ tidx)
{
  int e = blockIdx.x * 256 + threadIdx.x;
  if (e >= MEDGE) return;
  int i = e / KNN;
  int j = nbr[e];
  int res = -1;
#pragma unroll
  for (int t = 0; t < KNN; ++t) {
    if (nbr[j * KNN + t] == i) { res = j * KNN + t; break; }
  }
  tidx[e] = res;
}

// ---------------------------------------------------------------------------
// a = sig(x@Wga+bga)*(x@Wa+ba), b likewise.  Streaming, no LDS, rt=2.
// ---------------------------------------------------------------------------
__global__ __launch_bounds__(256)
void gemm_ab(const _Float16* __restrict__ xln,
             const _Float16* __restrict__ wa,  const float* __restrict__ ba,
             const _Float16* __restrict__ wga, const float* __restrict__ bga,
             const _Float16* __restrict__ wb,  const float* __restrict__ bb,
             const _Float16* __restrict__ wgb, const float* __restrict__ bgb,
             _Float16* __restrict__ aout, _Float16* __restrict__ bout)
{
  const int lane = threadIdx.x & 63;
  const int quad = lane >> 4;
  const int l16 = lane & 15;
  const int gw = blockIdx.x * 4 + (threadIdx.x >> 6);
  const int base = gw * 32;
  const int chbase = quad * 16 + l16;

  half8 xf[2][4];
#pragma unroll
  for (int rt = 0; rt < 2; ++rt)
#pragma unroll
    for (int kt = 0; kt < 4; ++kt)
      xf[rt][kt] = *(const half8*)(xln + (size_t)(base + rt * 16 + l16) * CH + kt * 32 + quad * 8);

  const half8* WA  = (const half8*)wa;
  const half8* WGA = (const half8*)wga;
  const half8* WB  = (const half8*)wb;
  const half8* WGB = (const half8*)wgb;

#pragma unroll
  for (int mt = 0; mt < 8; ++mt) {
    f32x4 aA[2], aGA[2], aB[2], aGB[2];
    const f32x4 z = {0.f, 0.f, 0.f, 0.f};
#pragma unroll
    for (int rt = 0; rt < 2; ++rt) { aA[rt] = z; aGA[rt] = z; aB[rt] = z; aGB[rt] = z; }
#pragma unroll
    for (int kt = 0; kt < 4; ++kt) {
      int ch = (mt * 4 + kt) * 64 + chbase;
      half8 wfa = WA[ch], wfga = WGA[ch], wfb = WB[ch], wfgb = WGB[ch];
#pragma unroll
      for (int rt = 0; rt < 2; ++rt) {
        aA[rt]  = __builtin_amdgcn_mfma_f32_16x16x32_f16(wfa,  xf[rt][kt], aA[rt], 0, 0, 0);
        aGA[rt] = __builtin_amdgcn_mfma_f32_16x16x32_f16(wfga, xf[rt][kt], aGA[rt], 0, 0, 0);
        aB[rt]  = __builtin_amdgcn_mfma_f32_16x16x32_f16(wfb,  xf[rt][kt], aB[rt], 0, 0, 0);
        aGB[rt] = __builtin_amdgcn_mfma_f32_16x16x32_f16(wfgb, xf[rt][kt], aGB[rt], 0, 0, 0);
      }
    }
    f32x4 bva  = *(const f32x4*)(ba  + mt * 16 + quad * 4);
    f32x4 bvga = *(const f32x4*)(bga + mt * 16 + quad * 4);
    f32x4 bvb  = *(const f32x4*)(bb  + mt * 16 + quad * 4);
    f32x4 bvgb = *(const f32x4*)(bgb + mt * 16 + quad * 4);
#pragma unroll
    for (int rt = 0; rt < 2; ++rt) {
      half4 av, bv;
#pragma unroll
      for (int r = 0; r < 4; ++r) {
        av[r] = (_Float16)(sigm_(aGA[rt][r] + bvga[r]) * (aA[rt][r] + bva[r]));
        bv[r] = (_Float16)(sigm_(aGB[rt][r] + bvgb[r]) * (aB[rt][r] + bvb[r]));
      }
      size_t off = (size_t)(base + rt * 16 + l16) * CH + mt * 16 + quad * 4;
      *(half4*)(aout + off) = av;
      *(half4*)(bout + off) = bv;
    }
  }
}

// ---------------------------------------------------------------------------
// sparse triangle einsum + fused LN -> kln f16
// ---------------------------------------------------------------------------
__global__ __launch_bounds__(256)
void tri_einsum_ln(const _Float16* __restrict__ a, const _Float16* __restrict__ b,
                   const int* __restrict__ nbr, const int* __restrict__ tidx,
                   const float* __restrict__ lng, const float* __restrict__ lnb,
                   _Float16* __restrict__ kout, int incoming)
{
  __shared__ float As[KNN][CH];
  __shared__ int bidx[KNN][KNN];
  __shared__ int nbr_s[KNN];
  __shared__ float part[6][4][2];
  const int n = blockIdx.x;
  const int tid = threadIdx.x;
  const int wv = tid >> 6;
  if (tid < KNN) nbr_s[tid] = nbr[n * KNN + tid];
  __syncthreads();
  if (tid < KNN * KNN) {
    int m = tid / KNN, t = tid - m * KNN;
    int j = nbr_s[m];
    bidx[m][t] = incoming ? tidx[j * KNN + t] : (j * KNN + t);
  }
  for (int idx = tid; idx < KNN * CH; idx += 256) {
    int t = idx >> 7, c = idx & 127;
    float av;
    if (incoming) {
      int ti = tidx[n * KNN + t];
      av = (ti >= 0) ? (float)(a[(size_t)ti * CH + c]) : 0.0f;
    } else {
      av = (float)(a[(size_t)(n * KNN + t) * CH + c]);
    }
    As[t][c] = av;
  }
  __syncthreads();
  const int c = tid & 127;
  const int mh = tid >> 7;
  const float gc = lng[c], bc = lnb[c];
  for (int mm = 0; mm < 6; ++mm) {
    int m = mm * 2 + mh;
    float acc = 0.0f;
#pragma unroll
    for (int t = 0; t < KNN; ++t) {
      int bi = bidx[m][t];
      float bv = (bi >= 0) ? (float)(b[(size_t)bi * CH + c]) : 0.0f;
      acc += As[t][c] * bv;
    }
    float s1 = wave_sum(acc);
    float s2 = wave_sum(acc * acc);
    if ((tid & 63) == 0) { part[mm][wv][0] = s1; part[mm][wv][1] = s2; }
    __syncthreads();
    int pb = mh * 2;
    float sum = part[mm][pb][0] + part[mm][pb + 1][0];
    float sq  = part[mm][pb][1] + part[mm][pb + 1][1];
    float mean = sum * (1.0f / 128.0f);
    float var = sq * (1.0f / 128.0f) - mean * mean;
    if (var < 0.0f) var = 0.0f;
    float rs = 1.0f / sqrtf(var + 1e-5f);
    kout[(size_t)(n * KNN + m) * CH + c] = (_Float16)((acc - mean) * rs * gc + bc);
  }
}

// ---------------------------------------------------------------------------
// v += sig(x@Wgo+bgo) * (kln@Wo + bo);  xln_next = LN(v)*g+b.  rt=1 streaming.
// ---------------------------------------------------------------------------
__global__ __launch_bounds__(256)
void out_go_gemm(const _Float16* __restrict__ kln,
                 const _Float16* __restrict__ wo,  const float* __restrict__ bo,
                 const _Float16* __restrict__ xln,
                 const _Float16* __restrict__ wgo, const float* __restrict__ bgo,
                 float* __restrict__ v,
                 const float* __restrict__ nlng, const float* __restrict__ nlnb,
                 _Float16* __restrict__ xlnN)
{
  const int lane = threadIdx.x & 63;
  const int quad = lane >> 4;
  const int l16 = lane & 15;
  const int gw = blockIdx.x * 4 + (threadIdx.x >> 6);
  const int base = gw * 16;
  const int chbase = quad * 16 + l16;
  const size_t rowOff = (size_t)(base + l16) * CH;

  half8 kf[4], xf[4];
#pragma unroll
  for (int kt = 0; kt < 4; ++kt) {
    kf[kt] = *(const half8*)(kln + rowOff + kt * 32 + quad * 8);
    xf[kt] = *(const half8*)(xln + rowOff + kt * 32 + quad * 8);
  }
  const half8* WO  = (const half8*)wo;
  const half8* WGO = (const half8*)wgo;

  f32x4 vn[8];
  float s = 0.0f, sq = 0.0f;
#pragma unroll
  for (int mt = 0; mt < 8; ++mt) {
    f32x4 aO = {0.f, 0.f, 0.f, 0.f}, aG = {0.f, 0.f, 0.f, 0.f};
#pragma unroll
    for (int kt = 0; kt < 4; ++kt) {
      int ch = (mt * 4 + kt) * 64 + chbase;
      aO = __builtin_amdgcn_mfma_f32_16x16x32_f16(WO[ch],  kf[kt], aO, 0, 0, 0);
      aG = __builtin_amdgcn_mfma_f32_16x16x32_f16(WGO[ch], xf[kt], aG, 0, 0, 0);
    }
    f32x4 bvo = *(const f32x4*)(bo  + mt * 16 + quad * 4);
    f32x4 bvg = *(const f32x4*)(bgo + mt * 16 + quad * 4);
    f32x4 vv = *(const f32x4*)(v + rowOff + mt * 16 + quad * 4);
#pragma unroll
    for (int r = 0; r < 4; ++r) {
      float nv = vv[r] + sigm_(aG[r] + bvg[r]) * (aO[r] + bvo[r]);
      vn[mt][r] = nv;
      s += nv;
      sq += nv * nv;
    }
    *(f32x4*)(v + rowOff + mt * 16 + quad * 4) = vn[mt];
  }
  s  += __shfl_xor(s, 16, 64);  s  += __shfl_xor(s, 32, 64);
  sq += __shfl_xor(sq, 16, 64); sq += __shfl_xor(sq, 32, 64);
  float mean = s * (1.0f / 128.0f);
  float var = sq * (1.0f / 128.0f) - mean * mean;
  if (var < 0.0f) var = 0.0f;
  float rs = 1.0f / sqrtf(var + 1e-5f);
#pragma unroll
  for (int mt = 0; mt < 8; ++mt) {
    f32x4 g4 = *(const f32x4*)(nlng + mt * 16 + quad * 4);
    f32x4 b4 = *(const f32x4*)(nlnb + mt * 16 + quad * 4);
    half4 o;
#pragma unroll
    for (int r = 0; r < 4; ++r)
      o[r] = (_Float16)((vn[mt][r] - mean) * rs * g4[r] + b4[r]);
    *(half4*)(xlnN + rowOff + mt * 16 + quad * 4) = o;
  }
}

// ---------------------------------------------------------------------------
// fused FFN: h = gelu(x@W1+b1) kept in LDS (f16); v += h@W2 + b2;
// xln_next = LN(v)*g+b.  Block = 32 rows, 4 waves cooperate.
// Phase1: wave w computes h couts [w*128,(w+1)*128).
// Phase2: wave w computes out couts [w*32,(w+1)*32) over full k=512.
// ---------------------------------------------------------------------------
__global__ __launch_bounds__(256)
void ffn_fused(const _Float16* __restrict__ xln,
               const _Float16* __restrict__ w1, const float* __restrict__ b1,
               const _Float16* __restrict__ w2, const float* __restrict__ b2,
               float* __restrict__ v,
               const float* __restrict__ nlng, const float* __restrict__ nlnb,
               _Float16* __restrict__ xlnN)
{
  __shared__ alignas(16) _Float16 hlds[32][FFD + 8];   // +8 halfs: 2-way bank alias (free)
  __shared__ float part[32][4][2];
  const int tid = threadIdx.x;
  const int lane = tid & 63;
  const int w = tid >> 6;
  const int quad = lane >> 4;
  const int l16 = lane & 15;
  const int rowBase = blockIdx.x * 32;
  const int chbase = quad * 16 + l16;

  half8 xf[2][4];
#pragma unroll
  for (int rt = 0; rt < 2; ++rt)
#pragma unroll
    for (int kt = 0; kt < 4; ++kt)
      xf[rt][kt] = *(const half8*)(xln + (size_t)(rowBase + rt * 16 + l16) * CH + kt * 32 + quad * 8);

  // phase 1
  const half8* W1 = (const half8*)w1;
#pragma unroll
  for (int mt = 0; mt < 8; ++mt) {
    int mtg = w * 8 + mt;
    f32x4 acc[2];
    const f32x4 z = {0.f, 0.f, 0.f, 0.f};
    acc[0] = z; acc[1] = z;
#pragma unroll
    for (int kt = 0; kt < 4; ++kt) {
      half8 wf = W1[(mtg * 4 + kt) * 64 + chbase];
#pragma unroll
      for (int rt = 0; rt < 2; ++rt)
        acc[rt] = __builtin_amdgcn_mfma_f32_16x16x32_f16(wf, xf[rt][kt], acc[rt], 0, 0, 0);
    }
    f32x4 bv = *(const f32x4*)(b1 + mtg * 16 + quad * 4);
#pragma unroll
    for (int rt = 0; rt < 2; ++rt) {
      half4 hh;
#pragma unroll
      for (int r = 0; r < 4; ++r)
        hh[r] = (_Float16)(gelu_(acc[rt][r] + bv[r]));
      *(half4*)&hlds[rt * 16 + l16][mtg * 16 + quad * 4] = hh;
    }
  }
  __syncthreads();

  // phase 2
  const half8* W2 = (const half8*)w2;
  f32x4 vn[2][2];
  float ssum[2] = {0.f, 0.f}, qsum[2] = {0.f, 0.f};
#pragma unroll
  for (int m2 = 0; m2 < 2; ++m2) {
    int mt = w * 2 + m2;
    f32x4 accA[2], accB[2];
    const f32x4 z = {0.f, 0.f, 0.f, 0.f};
    accA[0] = z; accA[1] = z; accB[0] = z; accB[1] = z;
#pragma unroll
    for (int kt = 0; kt < 16; kt += 2) {
      half8 wf0 = W2[(mt * 16 + kt) * 64 + chbase];
      half8 wf1 = W2[(mt * 16 + kt + 1) * 64 + chbase];
#pragma unroll
      for (int rt = 0; rt < 2; ++rt) {
        half8 hf0 = *(const half8*)&hlds[rt * 16 + l16][kt * 32 + quad * 8];
        half8 hf1 = *(const half8*)&hlds[rt * 16 + l16][(kt + 1) * 32 + quad * 8];
        accA[rt] = __builtin_amdgcn_mfma_f32_16x16x32_f16(wf0, hf0, accA[rt], 0, 0, 0);
        accB[rt] = __builtin_amdgcn_mfma_f32_16x16x32_f16(wf1, hf1, accB[rt], 0, 0, 0);
      }
    }
    f32x4 bv = *(const f32x4*)(b2 + mt * 16 + quad * 4);
#pragma unroll
    for (int rt = 0; rt < 2; ++rt) {
      size_t off = (size_t)(rowBase + rt * 16 + l16) * CH + mt * 16 + quad * 4;
      f32x4 vv = *(const f32x4*)(v + off);
#pragma unroll
      for (int r = 0; r < 4; ++r) {
        float nv = vv[r] + accA[rt][r] + accB[rt][r] + bv[r];
        vn[m2][rt][r] = nv;
        ssum[rt] += nv;
        qsum[rt] += nv * nv;
      }
      *(f32x4*)(v + off) = vn[m2][rt];
    }
  }
  // per-row partial sums (this wave covers couts w*32..w*32+31)
#pragma unroll
  for (int rt = 0; rt < 2; ++rt) {
    float s = ssum[rt], q = qsum[rt];
    s += __shfl_xor(s, 16, 64); s += __shfl_xor(s, 32, 64);
    q += __shfl_xor(q, 16, 64); q += __shfl_xor(q, 32, 64);
    if (quad == 0) { part[rt * 16 + l16][w][0] = s; part[rt * 16 + l16][w][1] = q; }
  }
  __syncthreads();
#pragma unroll
  for (int rt = 0; rt < 2; ++rt) {
    int row = rt * 16 + l16;
    float s = part[row][0][0] + part[row][1][0] + part[row][2][0] + part[row][3][0];
    float q = part[row][0][1] + part[row][1][1] + part[row][2][1] + part[row][3][1];
    float mean = s * (1.0f / 128.0f);
    float var = q * (1.0f / 128.0f) - mean * mean;
    if (var < 0.0f) var = 0.0f;
    float rs = 1.0f / sqrtf(var + 1e-5f);
#pragma unroll
    for (int m2 = 0; m2 < 2; ++m2) {
      int mt = w * 2 + m2;
      f32x4 g4 = *(const f32x4*)(nlng + mt * 16 + quad * 4);
      f32x4 b4 = *(const f32x4*)(nlnb + mt * 16 + quad * 4);
      half4 o;
#pragma unroll
      for (int r = 0; r < 4; ++r)
        o[r] = (_Float16)((vn[m2][rt][r] - mean) * rs * g4[r] + b4[r]);
      *(half4*)(xlnN + (size_t)(rowBase + row) * CH + mt * 16 + quad * 4) = o;
    }
  }
}

// ---------------------------------------------------------------------------
// final: s = v + transpose(v); e = s@decW + decb; write dense row
// ---------------------------------------------------------------------------
__global__ __launch_bounds__(256)
void decode_row(const float* __restrict__ vin, const int* __restrict__ tidx,
                const int* __restrict__ nbr, const float* __restrict__ decW,
                const float* __restrict__ decB, float* __restrict__ out)
{
  __shared__ float ev[KNN];
  __shared__ int nbr_s[KNN];
  const int n = blockIdx.x;
  const int tid = threadIdx.x;
  const int lane = tid & 63;
  const int w = tid >> 6;
  if (tid < KNN) nbr_s[tid] = nbr[n * KNN + tid];
  float dw1 = decW[lane], dw2 = decW[lane + 64];
  for (int k = w; k < KNN; k += 4) {
    int e = n * KNN + k;
    int ti = tidx[e];
    float s1 = vin[(size_t)e * CH + lane];
    float s2 = vin[(size_t)e * CH + 64 + lane];
    if (ti >= 0) {
      s1 += vin[(size_t)ti * CH + lane];
      s2 += vin[(size_t)ti * CH + 64 + lane];
    }
    float tot = wave_sum(s1 * dw1 + s2 * dw2);
    if (lane == 0) ev[k] = tot + decB[0];
  }
  __syncthreads();
  float4 z = make_float4(0.f, 0.f, 0.f, 0.f);
  float4* row = (float4*)(out + (size_t)n * NPTS);
  for (int idx = tid; idx < NPTS / 4; idx += 256) row[idx] = z;
  __syncthreads();
  if (tid < KNN) out[(size_t)n * NPTS + nbr_s[tid]] = ev[tid];
}

// ---------------------------------------------------------------------------
extern "C" void kernel_launch(void* const* d_in, const int* in_sizes, int n_in,
                              void* d_out, int out_size, void* d_ws, size_t ws_size,
                              hipStream_t stream)
{
  (void)in_sizes; (void)n_in; (void)out_size; (void)ws_size;
  const float* coords  = (const float*)d_in[0];
  const float* t_ln_g  = (const float*)d_in[1];
  const float* t_ln_b  = (const float*)d_in[2];
  const float* t_Wa    = (const float*)d_in[3];
  const float* t_ba    = (const float*)d_in[4];
  const float* t_Wga   = (const float*)d_in[5];
  const float* t_bga   = (const float*)d_in[6];
  const float* t_Wb    = (const float*)d_in[7];
  const float* t_bb    = (const float*)d_in[8];
  const float* t_Wgb   = (const float*)d_in[9];
  const float* t_bgb   = (const float*)d_in[10];
  const float* t_Wo    = (const float*)d_in[11];
  const float* t_bo    = (const float*)d_in[12];
  const float* t_Wgo   = (const float*)d_in[13];
  const float* t_bgo   = (const float*)d_in[14];
  const float* t_lno_g = (const float*)d_in[15];
  const float* t_lno_b = (const float*)d_in[16];
  const float* f_ln_g  = (const float*)d_in[17];
  const float* f_ln_b  = (const float*)d_in[18];
  const float* f_W1    = (const float*)d_in[19];
  const float* f_b1    = (const float*)d_in[20];
  const float* f_W2    = (const float*)d_in[21];
  const float* f_b2    = (const float*)d_in[22];
  const float* dec_W   = (const float*)d_in[23];
  const float* dec_b   = (const float*)d_in[24];

  const size_t NKC = (size_t)MEDGE * CH;   // 12,582,912
  char* ws = (char*)d_ws;
  float* v        = (float*)(ws);                       // 50.3 MB
  _Float16* kln   = (_Float16*)(ws + NKC * 4);          // 25.2 MB
  _Float16* xln   = (_Float16*)(ws + NKC * 6);          // 25.2 MB
  int* nbr        = (int*)(ws + NKC * 8);
  int* tidx       = (int*)(ws + NKC * 8 + (size_t)MEDGE * 4);
  float4* coords4 = (float4*)(ws + NKC * 8 + (size_t)MEDGE * 8);
  _Float16* wbase = (_Float16*)(ws + NKC * 8 + (size_t)MEDGE * 8 + NPTS * 16);
  const size_t TRIH = (size_t)12 * 2048 * 8;   // halfs per tri weight tensor
  _Float16* wA  = wbase;
  _Float16* wGA = wA  + TRIH;
  _Float16* wB  = wGA + TRIH;
  _Float16* wGB = wB  + TRIH;
  _Float16* wGO = wGB + TRIH;
  _Float16* wO  = wGO + TRIH;
  _Float16* w1  = wO  + TRIH;                  // 6 * 8192 * 8 halfs
  _Float16* w2  = w1  + (size_t)6 * 8192 * 8;

  // scratch inside d_out (free until decode_row)
  _Float16* abuf = (_Float16*)d_out;
  _Float16* bbuf = abuf + NKC;

  prep_coords<<<32, 256, 0, stream>>>(coords, coords4);

  SwzArgs sa;
  sa.src[0] = t_Wa;  sa.dst[0] = wA;  sa.K[0] = CH;  sa.N[0] = CH;  sa.B[0] = 12; sa.perB[0] = 2048;
  sa.src[1] = t_Wga; sa.dst[1] = wGA; sa.K[1] = CH;  sa.N[1] = CH;  sa.B[1] = 12; sa.perB[1] = 2048;
  sa.src[2] = t_Wb;  sa.dst[2] = wB;  sa.K[2] = CH;  sa.N[2] = CH;  sa.B[2] = 12; sa.perB[2] = 2048;
  sa.src[3] = t_Wgb; sa.dst[3] = wGB; sa.K[3] = CH;  sa.N[3] = CH;  sa.B[3] = 12; sa.perB[3] = 2048;
  sa.src[4] = t_Wgo; sa.dst[4] = wGO; sa.K[4] = CH;  sa.N[4] = CH;  sa.B[4] = 12; sa.perB[4] = 2048;
  sa.src[5] = t_Wo;  sa.dst[5] = wO;  sa.K[5] = CH;  sa.N[5] = CH;  sa.B[5] = 12; sa.perB[5] = 2048;
  sa.src[6] = f_W1;  sa.dst[6] = w1;  sa.K[6] = CH;  sa.N[6] = FFD; sa.B[6] = 6;  sa.perB[6] = 8192;
  sa.src[7] = f_W2;  sa.dst[7] = w2;  sa.K[7] = FFD; sa.N[7] = CH;  sa.B[7] = 6;  sa.perB[7] = 8192;
  dim3 pgrid(192, 8);
  prep_weights_swz<<<pgrid, 256, 0, stream>>>(sa);

  knn_embed<<<NPTS, 256, 0, stream>>>(coords4, t_ln_g, t_ln_b, nbr, v, xln);
  build_tidx<<<MEDGE / 256, 256, 0, stream>>>(nbr, tidx);

  const int G32 = MEDGE / (4 * 32);   // 768 blocks (rt=2)
  const int G16 = MEDGE / (4 * 16);   // 1536 blocks (rt=1)
  const int GFF = MEDGE / 32;         // 3072 blocks (block=32 rows)

  for (int l = 0; l < 6; ++l) {
    for (int rc = 0; rc < 2; ++rc) {
      int s = l * 2 + rc;
      gemm_ab<<<G32, 256, 0, stream>>>(xln,
          wA  + (size_t)s * 2048 * 8, t_ba  + s * CH,
          wGA + (size_t)s * 2048 * 8, t_bga + s * CH,
          wB  + (size_t)s * 2048 * 8, t_bb  + s * CH,
          wGB + (size_t)s * 2048 * 8, t_bgb + s * CH,
          abuf, bbuf);
      tri_einsum_ln<<<NPTS, 256, 0, stream>>>(abuf, bbuf, nbr, tidx,
          t_lno_g + s * CH, t_lno_b + s * CH, kln, rc);
      const float* ng = (rc == 0) ? (t_ln_g + (s + 1) * CH) : (f_ln_g + l * CH);
      const float* nb = (rc == 0) ? (t_ln_b + (s + 1) * CH) : (f_ln_b + l * CH);
      out_go_gemm<<<G16, 256, 0, stream>>>(kln,
          wO  + (size_t)s * 2048 * 8, t_bo  + s * CH,
          xln,
          wGO + (size_t)s * 2048 * 8, t_bgo + s * CH,
          v, ng, nb, xln);
    }
    const float* ng = (l < 5) ? (t_ln_g + (l + 1) * 2 * CH) : t_ln_g;
    const float* nb = (l < 5) ? (t_ln_b + (l + 1) * 2 * CH) : t_ln_b;
    ffn_fused<<<GFF, 256, 0, stream>>>(xln,
        w1 + (size_t)l * 8192 * 8, f_b1 + l * FFD,
        w2 + (size_t)l * 8192 * 8, f_b2 + l * CH,
        v, ng, nb, xln);
  }

  decode_row<<<NPTS, 256, 0, stream>>>(v, tidx, nbr, dec_W, dec_b, (float*)d_out);
}